// Round 8
// baseline (195.372 us; speedup 1.0000x reference)
//
#include <hip/hip_runtime.h>
#include <math.h>

// Problem constants
#define BATCH 8
#define DIMD  512
#define NTOK  1024      // H*W
#define NH    8
#define CQKV  640       // 64 K + 64 V + 512 Q
#define DOUT  512

typedef __attribute__((ext_vector_type(8))) short short8;   // MFMA A/B frag (8 bf16)
typedef __attribute__((ext_vector_type(4))) short short4v;
typedef __attribute__((ext_vector_type(4))) float f32x4;    // MFMA C/D frag

__device__ __forceinline__ short bf16rn(float x) {
    unsigned u = __float_as_uint(x);
    u += 0x7FFF + ((u >> 16) & 1);
    return (short)(u >> 16);
}
__device__ __forceinline__ short bf16tr(float x) {          // truncate (P only)
    return (short)(__float_as_uint(x) >> 16);
}
__device__ __forceinline__ float bf16tof(short s) {
    return __uint_as_float(((unsigned)(unsigned short)s) << 16);
}
struct HL { short h, l; };
__device__ __forceinline__ HL bf16split(float x) {
    HL r;
    r.h = bf16rn(x);
    r.l = bf16rn(x - bf16tof(r.h));
    return r;
}
// async global->LDS, 16B/lane; LDS dest = wave-uniform base + lane*16
__device__ __forceinline__ void dma16(const short* g, short* l) {
    __builtin_amdgcn_global_load_lds(
        (const __attribute__((address_space(1))) unsigned int*)g,
        (__attribute__((address_space(3))) unsigned int*)l, 16, 0, 0);
}

// Fragment-order conventions (verified end-to-end R2/R4/R5/R6/R7):
//  A-frag: lane=(q=lane>>4, r=lane&15), element A[m=r][k=q*8+j] per 32-k chunk
//  B-frag: element B[ncol=r][k=q*8+j]
//  C/D   : D[m=q*4+reg][ncol=r]
// Global frag buffers: [tile16][kchunk32][lane64][j8] = 512 shorts/chunk

// ---------------------------------------------------------------------------
// prepack_w: Wcat[d][c] -> B-frag hi/lo  Whi/Wlo[ct40][kt16][lane][8]
// ---------------------------------------------------------------------------
__global__ void prepack_w(const float* __restrict__ qp, const float* __restrict__ kp,
                          const float* __restrict__ vp,
                          short* __restrict__ whi, short* __restrict__ wlo) {
    int tid = blockIdx.x * 256 + threadIdx.x;           // 40960
    int lane = tid & 63, kt = (tid >> 6) & 15, ct = tid >> 10;
    int q = lane >> 4, r = lane & 15;
    int c = ct * 16 + r;
    short8 h, l;
    #pragma unroll
    for (int j = 0; j < 8; ++j) {
        int d = kt * 32 + q * 8 + j;
        float v;
        if (c < 64)       v = kp[d * 64 + c];
        else if (c < 128) v = vp[d * 64 + (c - 64)];
        else              v = qp[(size_t)(c - 128) * DIMD + d];
        HL s = bf16split(v);
        h[j] = s.h; l[j] = s.l;
    }
    *(short8*)&whi[(size_t)tid * 8] = h;
    *(short8*)&wlo[(size_t)tid * 8] = l;
}

// ---------------------------------------------------------------------------
// prepack_x: x[b][d][n] -> A-frag hi/lo  Xhi/Xlo[b][mt64][kt16][lane][8]
// ---------------------------------------------------------------------------
__global__ void prepack_x(const float* __restrict__ x,
                          short* __restrict__ xhi, short* __restrict__ xlo) {
    int tid = blockIdx.x * 256 + threadIdx.x;           // 524288
    int lane = tid & 63, kt = (tid >> 6) & 15, mt = (tid >> 10) & 63, b = tid >> 16;
    int q = lane >> 4, r = lane & 15;
    const float* src = x + ((size_t)b * DIMD + kt * 32 + q * 8) * NTOK + mt * 16 + r;
    short8 h, l;
    #pragma unroll
    for (int j = 0; j < 8; ++j) {
        HL s = bf16split(src[(size_t)j * NTOK]);
        h[j] = s.h; l[j] = s.l;
    }
    *(short8*)&xhi[(size_t)tid * 8] = h;
    *(short8*)&xlo[(size_t)tid * 8] = l;
}

// ---------------------------------------------------------------------------
// qkv_gemm: split-bf16 MFMA.  BM=64(n) BN=64(c) BK=64(d), 4 waves,
// grid (10,16,8)=1280 blocks, 5 blocks/CU (LDS 32 KB) — unchanged.
// ---------------------------------------------------------------------------
__global__ __launch_bounds__(256) void qkv_gemm(const short* __restrict__ xhi,
                                                const short* __restrict__ xlo,
                                                const short* __restrict__ whi,
                                                const short* __restrict__ wlo,
                                                float* __restrict__ qkv) {
    __shared__ short Ah[4096], Al[4096];    // [mtl4][kc2][lane][8]
    __shared__ short Bh[4096], Bl[4096];    // [ctl4][kc2][lane][8]
    const int b = blockIdx.z, bm = blockIdx.y, cb = blockIdx.x;
    const int tid = threadIdx.x, w = tid >> 6, lane = tid & 63;
    const int q = lane >> 4, r = lane & 15;
    f32x4 acc[4];
    #pragma unroll
    for (int j = 0; j < 4; ++j) acc[j] = (f32x4){0.f, 0.f, 0.f, 0.f};

    for (int it = 0; it < 8; ++it) {
        __syncthreads();
        for (int u = w; u < 8; u += 4) {
            size_t ga = ((size_t)((b * 64 + bm * 4 + (u >> 1)) * 16 + it * 2 + (u & 1))) * 512 + lane * 8;
            dma16(xhi + ga, &Ah[u * 512]);
            dma16(xlo + ga, &Al[u * 512]);
            size_t gb = ((size_t)((cb * 4 + (u >> 1)) * 16 + it * 2 + (u & 1))) * 512 + lane * 8;
            dma16(whi + gb, &Bh[u * 512]);
            dma16(wlo + gb, &Bl[u * 512]);
        }
        __syncthreads();
        #pragma unroll
        for (int kc = 0; kc < 2; ++kc) {
            short8 ah = *(short8*)&Ah[(w * 2 + kc) * 512 + lane * 8];
            short8 al = *(short8*)&Al[(w * 2 + kc) * 512 + lane * 8];
            #pragma unroll
            for (int tt = 0; tt < 4; ++tt) {
                short8 bh = *(short8*)&Bh[(tt * 2 + kc) * 512 + lane * 8];
                short8 bl = *(short8*)&Bl[(tt * 2 + kc) * 512 + lane * 8];
                acc[tt] = __builtin_amdgcn_mfma_f32_16x16x32_bf16(ah, bh, acc[tt], 0, 0, 0);
                acc[tt] = __builtin_amdgcn_mfma_f32_16x16x32_bf16(ah, bl, acc[tt], 0, 0, 0);
                acc[tt] = __builtin_amdgcn_mfma_f32_16x16x32_bf16(al, bh, acc[tt], 0, 0, 0);
            }
        }
    }
    const int n_base = bm * 64 + w * 16;
    #pragma unroll
    for (int reg = 0; reg < 4; ++reg)
        #pragma unroll
        for (int tt = 0; tt < 4; ++tt)
            qkv[((size_t)b * NTOK + n_base + q * 4 + reg) * CQKV
                + cb * 64 + tt * 16 + r] = acc[tt][reg];
}

// ---------------------------------------------------------------------------
// prepack_kv: qkv fp32 -> K hi/lo + V bf16 in B-frag order per 64-row tile.
// ---------------------------------------------------------------------------
__global__ void prepack_kv(const float* __restrict__ qkv, short* __restrict__ khi,
                           short* __restrict__ klo, short* __restrict__ vf) {
    int tid = blockIdx.x * 256 + threadIdx.x;           // 131072
    int lane = tid & 63, q = lane >> 4, r = lane & 15;
    int half = tid >> 16;
    int u = tid & 0xFFFF;
    int ic = (u >> 6) & 7, t = (u >> 9) & 15, b = u >> 13;
    if (half == 0) {
        int i = ic >> 1, c = ic & 1;
        const float* src = qkv + ((size_t)b * NTOK + t * 64 + i * 16 + r) * CQKV + c * 32 + q * 8;
        short8 h, l;
        #pragma unroll
        for (int j = 0; j < 8; ++j) {
            HL s = bf16split(src[j]);
            h[j] = s.h; l[j] = s.l;
        }
        *(short8*)&khi[(size_t)u * 8] = h;
        *(short8*)&klo[(size_t)u * 8] = l;
    } else {
        int tv = ic >> 1, cc = ic & 1;
        const float* src = qkv + ((size_t)b * NTOK + t * 64 + cc * 32 + q * 8) * CQKV + 64 + tv * 16 + r;
        short8 v;
        #pragma unroll
        for (int j = 0; j < 8; ++j) v[j] = bf16rn(src[(size_t)j * CQKV]);
        *(short8*)&vf[(size_t)u * 8] = v;
    }
}

// ---------------------------------------------------------------------------
// prepack_wout: out_proj fp32 -> A-frag bf16  Wof[mt32][kt16][lane][8]
// ---------------------------------------------------------------------------
__global__ void prepack_wout(const float* __restrict__ wout, short* __restrict__ wof) {
    int tid = blockIdx.x * 256 + threadIdx.x;           // 32768
    int lane = tid & 63, kt = (tid >> 6) & 15, mt = tid >> 10;
    int q = lane >> 4, r = lane & 15;
    const float* src = wout + (size_t)(mt * 16 + r) * DOUT + kt * 32 + q * 8;
    short8 h;
    #pragma unroll
    for (int j = 0; j < 8; ++j) h[j] = bf16rn(src[j]);
    *(short8*)&wof[(size_t)tid * 8] = h;
}

// ---------------------------------------------------------------------------
// attn: MFMA flash attention — R7 math, double-buffered K/V staging.
// Per tile: ONE barrier, then issue async DMA for tile t+1 into the other
// buffer, then compute tile t — the compiler's vmcnt(0)-before-barrier now
// drains loads that have had a full compute phase to land.
// Block = 256 thr (4 waves), 128 Q-rows, 2 row-tiles/wave; grid 512.
// LDS = 3*2*8 KB (K/V dbuf) + 18 KB (P) = 66 KB -> 2 blocks/CU.
// P is per-wave-private (no barrier needed around it; verified R2-R7).
// ---------------------------------------------------------------------------
__global__ __launch_bounds__(256) void attn_mfma(const float* __restrict__ qkv,
                                                 const short* __restrict__ khi_g,
                                                 const short* __restrict__ klo_g,
                                                 const short* __restrict__ vf_g,
                                                 short* __restrict__ ob) {
    __shared__ short Khi[2][4096], Klo[2][4096], Vf[2][4096];
    __shared__ short Pbuf[4 * 64 * 36];     // per-wave P col-major [m64][rows32 pad36]
    const int b   = blockIdx.z;
    const int h   = blockIdx.y;
    const int n0  = blockIdx.x * 128;
    const int tid = threadIdx.x;
    const int w    = tid >> 6;              // 4 waves
    const int lane = tid & 63;
    const int q    = lane >> 4;
    const int r    = lane & 15;
    const float* base = qkv + (size_t)b * NTOK * CQKV;
    short* Pw = Pbuf + w * (64 * 36);

    // Q fragments (A layout), scale*log2e folded, split hi/lo
    const float qscale = 0.125f * 1.44269504f;   // 64^-0.5 * log2(e)
    short8 qhi[2][2], qlo[2][2];                 // [row-tile][k-chunk]
    #pragma unroll
    for (int rt = 0; rt < 2; ++rt) {
        #pragma unroll
        for (int c = 0; c < 2; ++c) {
            const float* qp = base + (size_t)(n0 + w * 32 + rt * 16 + r) * CQKV
                              + 128 + h * 64 + c * 32 + q * 8;
            float4 a0 = *(const float4*)qp;
            float4 a1 = *(const float4*)(qp + 4);
            float vals[8] = {a0.x, a0.y, a0.z, a0.w, a1.x, a1.y, a1.z, a1.w};
            #pragma unroll
            for (int j = 0; j < 8; ++j) {
                HL s = bf16split(vals[j] * qscale);
                qhi[rt][c][j] = s.h;
                qlo[rt][c][j] = s.l;
            }
        }
    }

    // ones B-frag (bf16 1.0) for the l = P*1 row-sum MFMA
    short8 bones;
    #pragma unroll
    for (int j = 0; j < 8; ++j) bones[j] = (short)0x3F80;

    f32x4 oacc[2][4], lacc[2];
    float m_[2][4];
    #pragma unroll
    for (int rt = 0; rt < 2; ++rt) {
        #pragma unroll
        for (int tt = 0; tt < 4; ++tt) oacc[rt][tt] = (f32x4){0.f, 0.f, 0.f, 0.f};
        lacc[rt] = (f32x4){0.f, 0.f, 0.f, 0.f};
        #pragma unroll
        for (int i = 0; i < 4; ++i) m_[rt][i] = -1e30f;
    }

    // prefetch tile 0 into buffer 0
    {
        const size_t kb = ((size_t)(b * 16) * 8) * 512;
        for (int ch = w; ch < 8; ch += 4) {
            dma16(khi_g + kb + ch * 512 + lane * 8, &Khi[0][ch * 512]);
            dma16(klo_g + kb + ch * 512 + lane * 8, &Klo[0][ch * 512]);
            dma16(vf_g  + kb + ch * 512 + lane * 8, &Vf [0][ch * 512]);
        }
    }

    for (int t = 0; t < 16; ++t) {
        const int cur = t & 1;
        // own-vmcnt drained before barrier (compiler) => buf[cur] ready for all
        // waves; all waves past compute(t-1) => buf[cur^1] free to overwrite.
        __syncthreads();
        if (t < 15) {
            const size_t kb = ((size_t)(b * 16 + t + 1) * 8) * 512;
            for (int ch = w; ch < 8; ch += 4) {
                dma16(khi_g + kb + ch * 512 + lane * 8, &Khi[cur ^ 1][ch * 512]);
                dma16(klo_g + kb + ch * 512 + lane * 8, &Klo[cur ^ 1][ch * 512]);
                dma16(vf_g  + kb + ch * 512 + lane * 8, &Vf [cur ^ 1][ch * 512]);
            }
        }

        // S (log2-scaled) = Q K^T  (hi*hi + hi*lo + lo*hi); kh/kl shared by 2 rt
        f32x4 s[2][4];
        #pragma unroll
        for (int rt = 0; rt < 2; ++rt)
            #pragma unroll
            for (int tt = 0; tt < 4; ++tt) s[rt][tt] = (f32x4){0.f, 0.f, 0.f, 0.f};
        #pragma unroll
        for (int c = 0; c < 2; ++c) {
            #pragma unroll
            for (int tt = 0; tt < 4; ++tt) {
                short8 kh = *(short8*)&Khi[cur][((tt * 2 + c) * 64 + lane) * 8];
                short8 kl = *(short8*)&Klo[cur][((tt * 2 + c) * 64 + lane) * 8];
                #pragma unroll
                for (int rt = 0; rt < 2; ++rt) {
                    s[rt][tt] = __builtin_amdgcn_mfma_f32_16x16x32_bf16(qhi[rt][c], kh, s[rt][tt], 0, 0, 0);
                    s[rt][tt] = __builtin_amdgcn_mfma_f32_16x16x32_bf16(qhi[rt][c], kl, s[rt][tt], 0, 0, 0);
                    s[rt][tt] = __builtin_amdgcn_mfma_f32_16x16x32_bf16(qlo[rt][c], kh, s[rt][tt], 0, 0, 0);
                }
            }
        }

        // online softmax (log2 space): max shuffles only; sum comes from MFMA
        #pragma unroll
        for (int rt = 0; rt < 2; ++rt) {
            #pragma unroll
            for (int reg = 0; reg < 4; ++reg) {
                float smax = fmaxf(fmaxf(s[rt][0][reg], s[rt][1][reg]),
                                   fmaxf(s[rt][2][reg], s[rt][3][reg]));
                #pragma unroll
                for (int off = 1; off < 16; off <<= 1)
                    smax = fmaxf(smax, __shfl_xor(smax, off, 16));
                float nm    = fmaxf(m_[rt][reg], smax);
                float alpha = exp2f(m_[rt][reg] - nm);
                m_[rt][reg] = nm;
                #pragma unroll
                for (int tt = 0; tt < 4; ++tt)
                    s[rt][tt][reg] = exp2f(s[rt][tt][reg] - nm);
                lacc[rt][reg] *= alpha;
                #pragma unroll
                for (int tt = 0; tt < 4; ++tt) oacc[rt][tt][reg] *= alpha;
            }
        }

        // P -> per-wave LDS (col-major, stride 36): b64 writes, truncation
        #pragma unroll
        for (int rt = 0; rt < 2; ++rt) {
            #pragma unroll
            for (int tt = 0; tt < 4; ++tt) {
                short4v p4;
                #pragma unroll
                for (int reg = 0; reg < 4; ++reg) p4[reg] = bf16tr(s[rt][tt][reg]);
                *(short4v*)&Pw[(r + 16 * tt) * 36 + rt * 16 + q * 4] = p4;
            }
        }

        // O += P V ; l += P 1  (vfr shared by both rt)
        #pragma unroll
        for (int c = 0; c < 2; ++c) {
            short8 pf[2];
            #pragma unroll
            for (int rt = 0; rt < 2; ++rt)
                #pragma unroll
                for (int j = 0; j < 8; ++j)
                    pf[rt][j] = Pw[(c * 32 + q * 8 + j) * 36 + rt * 16 + r];
            #pragma unroll
            for (int rt = 0; rt < 2; ++rt)
                lacc[rt] = __builtin_amdgcn_mfma_f32_16x16x32_bf16(pf[rt], bones, lacc[rt], 0, 0, 0);
            #pragma unroll
            for (int tt = 0; tt < 4; ++tt) {
                short8 vfr = *(short8*)&Vf[cur][((tt * 2 + c) * 64 + lane) * 8];
                #pragma unroll
                for (int rt = 0; rt < 2; ++rt)
                    oacc[rt][tt] = __builtin_amdgcn_mfma_f32_16x16x32_bf16(pf[rt], vfr, oacc[rt][tt], 0, 0, 0);
            }
        }
    }

    // epilogue: normalize, write O as bf16 B-frags (layout verified R4-R7)
    #pragma unroll
    for (int rt = 0; rt < 2; ++rt) {
        const int nt = blockIdx.x * 8 + w * 2 + rt;
        #pragma unroll
        for (int reg = 0; reg < 4; ++reg) {
            float inv = 1.f / lacc[rt][reg];
            #pragma unroll
            for (int tt = 0; tt < 4; ++tt) {
                int ct = h * 2 + (tt >> 1);
                int lanep = ((tt & 1) * 2 + (r >> 3)) * 16 + q * 4 + reg;
                ob[((((size_t)b * 64 + nt) * 16 + ct) * 64 + lanep) * 8 + (r & 7)] =
                    bf16rn(oacc[rt][tt][reg] * inv);
            }
        }
    }
}

// ---------------------------------------------------------------------------
// out_gemm: plain bf16 MFMA, double-buffered staging (same pipeline as attn).
// BM=64(d) BN=64(n) BK=64(c), 4 waves, grid (16,8,8)=1024 blocks; LDS 32 KB.
// ---------------------------------------------------------------------------
__global__ __launch_bounds__(256) void out_gemm(const short* __restrict__ wof,
                                                const short* __restrict__ obf,
                                                float* __restrict__ out) {
    __shared__ short Ah[2][4096];   // [mtl4][kc2][lane][8]
    __shared__ short Bh[2][4096];   // [ntl4][kc2][lane][8]
    const int b = blockIdx.z, bd = blockIdx.y, bn = blockIdx.x;
    const int tid = threadIdx.x, w = tid >> 6, lane = tid & 63;
    const int q = lane >> 4, r = lane & 15;
    f32x4 acc[4];
    #pragma unroll
    for (int j = 0; j < 4; ++j) acc[j] = (f32x4){0.f, 0.f, 0.f, 0.f};

    // prefetch it=0 into buffer 0
    for (int u = w; u < 8; u += 4) {
        size_t ga = ((size_t)((bd * 4 + (u >> 1)) * 16 + (u & 1))) * 512 + lane * 8;
        dma16(wof + ga, &Ah[0][u * 512]);
        size_t gb = ((size_t)((b * 64 + bn * 4 + (u >> 1)) * 16 + (u & 1))) * 512 + lane * 8;
        dma16(obf + gb, &Bh[0][u * 512]);
    }

    for (int it = 0; it < 8; ++it) {
        const int cur = it & 1;
        __syncthreads();
        if (it < 7) {
            for (int u = w; u < 8; u += 4) {
                size_t ga = ((size_t)((bd * 4 + (u >> 1)) * 16 + (it + 1) * 2 + (u & 1))) * 512 + lane * 8;
                dma16(wof + ga, &Ah[cur ^ 1][u * 512]);
                size_t gb = ((size_t)((b * 64 + bn * 4 + (u >> 1)) * 16 + (it + 1) * 2 + (u & 1))) * 512 + lane * 8;
                dma16(obf + gb, &Bh[cur ^ 1][u * 512]);
            }
        }
        #pragma unroll
        for (int kc = 0; kc < 2; ++kc) {
            short8 a = *(short8*)&Ah[cur][(w * 2 + kc) * 512 + lane * 8];
            #pragma unroll
            for (int tt = 0; tt < 4; ++tt) {
                short8 bb = *(short8*)&Bh[cur][(tt * 2 + kc) * 512 + lane * 8];
                acc[tt] = __builtin_amdgcn_mfma_f32_16x16x32_bf16(a, bb, acc[tt], 0, 0, 0);
            }
        }
    }
    const int d_base = bd * 64 + w * 16;
    #pragma unroll
    for (int reg = 0; reg < 4; ++reg)
        #pragma unroll
        for (int tt = 0; tt < 4; ++tt)
            out[((size_t)b * DOUT + d_base + q * 4 + reg) * NTOK
                + bn * 64 + tt * 16 + r] = acc[tt][reg];
}

// ---------------------------------------------------------------------------
extern "C" void kernel_launch(void* const* d_in, const int* in_sizes, int n_in,
                              void* d_out, int out_size, void* d_ws, size_t ws_size,
                              hipStream_t stream) {
    const float* x  = (const float*)d_in[0];
    const float* qp = (const float*)d_in[1];
    const float* kp = (const float*)d_in[2];
    const float* vp = (const float*)d_in[3];
    const float* op = (const float*)d_in[4];
    float* out = (float*)d_out;

    // workspace layout (39.06 MB total, with aliasing — proven R4-R7)
    short* Whi = (short*)d_ws;                 // 327,680 shorts
    short* Wlo = Whi + 327680;                 // 327,680
    short* Xhi = Wlo + 327680;                 // 4,194,304
    short* Xlo = Xhi + 4194304;                // 4,194,304
    float* qkvb = (float*)(Xlo + 4194304);     // 5,242,880 floats
    // aliases (safe by stream ordering):
    short* Ob  = Xhi;                          // written in attn, after Xhi dead
    short* Wof = Xlo;                          // 262,144 shorts
    short* Khi = Xlo + 262144;                 // 524,288
    short* Klo = Khi + 524288;                 // 524,288
    short* Vf  = Klo + 524288;                 // 524,288

    prepack_w   <<<160,  256, 0, stream>>>(qp, kp, vp, Whi, Wlo);
    prepack_x   <<<2048, 256, 0, stream>>>(x, Xhi, Xlo);
    qkv_gemm    <<<dim3(10, 16, BATCH), 256, 0, stream>>>(Xhi, Xlo, Whi, Wlo, qkvb);
    prepack_kv  <<<512,  256, 0, stream>>>(qkvb, Khi, Klo, Vf);
    prepack_wout<<<128,  256, 0, stream>>>(op, Wof);
    attn_mfma   <<<dim3(8, NH, BATCH), 256, 0, stream>>>(qkvb, Khi, Klo, Vf, Ob);
    out_gemm    <<<dim3(16, 8, BATCH), 256, 0, stream>>>(Wof, Ob, out);
}

// Round 9
// 193.121 us; speedup vs baseline: 1.0117x; 1.0117x over previous
//
#include <hip/hip_runtime.h>
#include <math.h>

// Problem constants
#define BATCH 8
#define DIMD  512
#define NTOK  1024      // H*W
#define NH    8
#define CQKV  640       // 64 K + 64 V + 512 Q
#define DOUT  512

typedef __attribute__((ext_vector_type(8))) short short8;   // MFMA A/B frag (8 bf16)
typedef __attribute__((ext_vector_type(4))) short short4v;
typedef __attribute__((ext_vector_type(4))) float f32x4;    // MFMA C/D frag

__device__ __forceinline__ short bf16rn(float x) {
    unsigned u = __float_as_uint(x);
    u += 0x7FFF + ((u >> 16) & 1);
    return (short)(u >> 16);
}
__device__ __forceinline__ short bf16tr(float x) {          // truncate (P only)
    return (short)(__float_as_uint(x) >> 16);
}
__device__ __forceinline__ float bf16tof(short s) {
    return __uint_as_float(((unsigned)(unsigned short)s) << 16);
}
struct HL { short h, l; };
__device__ __forceinline__ HL bf16split(float x) {
    HL r;
    r.h = bf16rn(x);
    r.l = bf16rn(x - bf16tof(r.h));
    return r;
}
// async global->LDS, 16B/lane; LDS dest = wave-uniform base + lane*16
__device__ __forceinline__ void dma16(const short* g, short* l) {
    __builtin_amdgcn_global_load_lds(
        (const __attribute__((address_space(1))) unsigned int*)g,
        (__attribute__((address_space(3))) unsigned int*)l, 16, 0, 0);
}

// Fragment-order conventions (verified end-to-end R2/R4-R8):
//  A-frag: lane=(q=lane>>4, r=lane&15), element A[m=r][k=q*8+j] per 32-k chunk
//  B-frag: element B[ncol=r][k=q*8+j]
//  C/D   : D[m=q*4+reg][ncol=r]
// K/V global frag buffers: [b][t16][ic8][lane64][j8] = 512 shorts/chunk
// Q global frag buffer:    [b][h][nt64][kc2][lane64][j8]

// ---------------------------------------------------------------------------
// prepack_w: Wcat[d][c] -> B-frag hi/lo  Whi/Wlo[ct40][kt16][lane][8]
// ---------------------------------------------------------------------------
__global__ void prepack_w(const float* __restrict__ qp, const float* __restrict__ kp,
                          const float* __restrict__ vp,
                          short* __restrict__ whi, short* __restrict__ wlo) {
    int tid = blockIdx.x * 256 + threadIdx.x;           // 40960
    int lane = tid & 63, kt = (tid >> 6) & 15, ct = tid >> 10;
    int q = lane >> 4, r = lane & 15;
    int c = ct * 16 + r;
    short8 h, l;
    #pragma unroll
    for (int j = 0; j < 8; ++j) {
        int d = kt * 32 + q * 8 + j;
        float v;
        if (c < 64)       v = kp[d * 64 + c];
        else if (c < 128) v = vp[d * 64 + (c - 64)];
        else              v = qp[(size_t)(c - 128) * DIMD + d];
        HL s = bf16split(v);
        h[j] = s.h; l[j] = s.l;
    }
    *(short8*)&whi[(size_t)tid * 8] = h;
    *(short8*)&wlo[(size_t)tid * 8] = l;
}

// ---------------------------------------------------------------------------
// prepack_x: x[b][d][n] -> A-frag hi/lo  Xhi/Xlo[b][mt64][kt16][lane][8]
// ---------------------------------------------------------------------------
__global__ void prepack_x(const float* __restrict__ x,
                          short* __restrict__ xhi, short* __restrict__ xlo) {
    int tid = blockIdx.x * 256 + threadIdx.x;           // 524288
    int lane = tid & 63, kt = (tid >> 6) & 15, mt = (tid >> 10) & 63, b = tid >> 16;
    int q = lane >> 4, r = lane & 15;
    const float* src = x + ((size_t)b * DIMD + kt * 32 + q * 8) * NTOK + mt * 16 + r;
    short8 h, l;
    #pragma unroll
    for (int j = 0; j < 8; ++j) {
        HL s = bf16split(src[(size_t)j * NTOK]);
        h[j] = s.h; l[j] = s.l;
    }
    *(short8*)&xhi[(size_t)tid * 8] = h;
    *(short8*)&xlo[(size_t)tid * 8] = l;
}

// ---------------------------------------------------------------------------
// qkv_gemm: split-bf16 MFMA + FUSED frag emission.
// BM=64(n) BN=64(c) BK=64(d), 4 waves, grid (10,16,8)=1280 blocks.
// Epilogue stages the C-tile through the (reused) 32KB LDS pool and emits:
//   cb==0 -> K tile as hi/lo B-frags (layout == old prepack_kv K)
//   cb==1 -> V tile as bf16 B-frags  (layout == old prepack_kv V)
//   cb>=2 -> Q head (cb-2) as hi/lo A-frags with qscale*log2e folded
// fp32 qkv intermediate + prepack_kv kernel are eliminated.
// ---------------------------------------------------------------------------
__global__ __launch_bounds__(256) void qkv_gemm(const short* __restrict__ xhi,
                                                const short* __restrict__ xlo,
                                                const short* __restrict__ whi,
                                                const short* __restrict__ wlo,
                                                short* __restrict__ khi,
                                                short* __restrict__ klo,
                                                short* __restrict__ vf,
                                                short* __restrict__ qhi,
                                                short* __restrict__ qlo) {
    __shared__ __align__(16) char pool[32768];
    short* Ah = (short*)pool;           // 4096 shorts
    short* Al = Ah + 4096;
    short* Bh = Al + 4096;
    short* Bl = Bh + 4096;
    float (*Cs)[65] = (float(*)[65])pool;   // 64*65*4 = 16640 B (aliases staging)

    const int b = blockIdx.z, bm = blockIdx.y, cb = blockIdx.x;
    const int tid = threadIdx.x, w = tid >> 6, lane = tid & 63;
    const int q = lane >> 4, r = lane & 15;
    f32x4 acc[4];
    #pragma unroll
    for (int j = 0; j < 4; ++j) acc[j] = (f32x4){0.f, 0.f, 0.f, 0.f};

    for (int it = 0; it < 8; ++it) {
        __syncthreads();
        for (int u = w; u < 8; u += 4) {
            size_t ga = ((size_t)((b * 64 + bm * 4 + (u >> 1)) * 16 + it * 2 + (u & 1))) * 512 + lane * 8;
            dma16(xhi + ga, &Ah[u * 512]);
            dma16(xlo + ga, &Al[u * 512]);
            size_t gb = ((size_t)((cb * 4 + (u >> 1)) * 16 + it * 2 + (u & 1))) * 512 + lane * 8;
            dma16(whi + gb, &Bh[u * 512]);
            dma16(wlo + gb, &Bl[u * 512]);
        }
        __syncthreads();
        #pragma unroll
        for (int kc = 0; kc < 2; ++kc) {
            short8 ah = *(short8*)&Ah[(w * 2 + kc) * 512 + lane * 8];
            short8 al = *(short8*)&Al[(w * 2 + kc) * 512 + lane * 8];
            #pragma unroll
            for (int tt = 0; tt < 4; ++tt) {
                short8 bh = *(short8*)&Bh[(tt * 2 + kc) * 512 + lane * 8];
                short8 bl = *(short8*)&Bl[(tt * 2 + kc) * 512 + lane * 8];
                acc[tt] = __builtin_amdgcn_mfma_f32_16x16x32_bf16(ah, bh, acc[tt], 0, 0, 0);
                acc[tt] = __builtin_amdgcn_mfma_f32_16x16x32_bf16(ah, bl, acc[tt], 0, 0, 0);
                acc[tt] = __builtin_amdgcn_mfma_f32_16x16x32_bf16(al, bh, acc[tt], 0, 0, 0);
            }
        }
    }

    // ---- fused epilogue: C tile -> LDS -> frag-order bf16 global ----
    __syncthreads();    // staging reads done; safe to overwrite pool
    #pragma unroll
    for (int reg = 0; reg < 4; ++reg)
        #pragma unroll
        for (int tt = 0; tt < 4; ++tt)
            Cs[w * 16 + q * 4 + reg][tt * 16 + r] = acc[tt][reg];
    __syncthreads();

    if (cb == 0) {
        // K: elem K[m = bm*64 + i*16 + r2][kd = cc*32 + q2*8 + j], ic = i*2+cc
        for (int u = tid; u < 512; u += 256) {
            int lane2 = u & 63, ic = u >> 6;
            int q2 = lane2 >> 4, r2 = lane2 & 15;
            int i = ic >> 1, cc = ic & 1;
            short8 h8, l8;
            #pragma unroll
            for (int j = 0; j < 8; ++j) {
                HL s = bf16split(Cs[i * 16 + r2][cc * 32 + q2 * 8 + j]);
                h8[j] = s.h; l8[j] = s.l;
            }
            size_t off = ((size_t)(b * 16 + bm) * 8 + ic) * 512 + lane2 * 8;
            *(short8*)&khi[off] = h8;
            *(short8*)&klo[off] = l8;
        }
    } else if (cb == 1) {
        // V: elem V[mloc = cc*32 + q2*8 + j][v = tv*16 + r2], ic = tv*2+cc
        for (int u = tid; u < 512; u += 256) {
            int lane2 = u & 63, ic = u >> 6;
            int q2 = lane2 >> 4, r2 = lane2 & 15;
            int tv = ic >> 1, cc = ic & 1;
            short8 v8;
            #pragma unroll
            for (int j = 0; j < 8; ++j)
                v8[j] = bf16rn(Cs[cc * 32 + q2 * 8 + j][tv * 16 + r2]);
            size_t off = ((size_t)(b * 16 + bm) * 8 + ic) * 512 + lane2 * 8;
            *(short8*)&vf[off] = v8;
        }
    } else {
        // Q head hd: elem Q[n = (bm*4+ntl)*16 + r2][kq = kc*32 + q2*8 + j],
        // scaled by 64^-0.5 * log2(e); ic = ntl*2+kc
        const int hd = cb - 2;
        const float qscale = 0.125f * 1.44269504f;
        for (int u = tid; u < 512; u += 256) {
            int lane2 = u & 63, ic = u >> 6;
            int q2 = lane2 >> 4, r2 = lane2 & 15;
            int ntl = ic >> 1, kc = ic & 1;
            short8 h8, l8;
            #pragma unroll
            for (int j = 0; j < 8; ++j) {
                HL s = bf16split(Cs[ntl * 16 + r2][kc * 32 + q2 * 8 + j] * qscale);
                h8[j] = s.h; l8[j] = s.l;
            }
            size_t off = ((((size_t)(b * 8 + hd) * 64 + bm * 4 + ntl) * 2 + kc) * 64 + lane2) * 8;
            *(short8*)&qhi[off] = h8;
            *(short8*)&qlo[off] = l8;
        }
    }
}

// ---------------------------------------------------------------------------
// prepack_wout: out_proj fp32 -> A-frag bf16  Wof[mt32][kt16][lane][8]
// ---------------------------------------------------------------------------
__global__ void prepack_wout(const float* __restrict__ wout, short* __restrict__ wof) {
    int tid = blockIdx.x * 256 + threadIdx.x;           // 32768
    int lane = tid & 63, kt = (tid >> 6) & 15, mt = tid >> 10;
    int q = lane >> 4, r = lane & 15;
    const float* src = wout + (size_t)(mt * 16 + r) * DOUT + kt * 32 + q * 8;
    short8 h;
    #pragma unroll
    for (int j = 0; j < 8; ++j) h[j] = bf16rn(src[j]);
    *(short8*)&wof[(size_t)tid * 8] = h;
}

// ---------------------------------------------------------------------------
// attn: MFMA flash attention — R7 structure (proven 76 µs) with Q read as
// prebuilt frags.  Block = 256 thr (4 waves), 128 Q-rows, 2 row-tiles/wave;
// grid (8,8,8)=512.  Single-buffer K/V staging (dbuf regressed — R8).
// log2-space softmax; row-sum l via ones-B-frag MFMA; P truncation.
// ---------------------------------------------------------------------------
__global__ __launch_bounds__(256) void attn_mfma(const short* __restrict__ qhi_g,
                                                 const short* __restrict__ qlo_g,
                                                 const short* __restrict__ khi_g,
                                                 const short* __restrict__ klo_g,
                                                 const short* __restrict__ vf_g,
                                                 short* __restrict__ ob) {
    __shared__ short Khi[4096], Klo[4096], Vf[4096];
    __shared__ short Pbuf[4 * 64 * 36];     // per-wave P col-major [m64][rows32 pad36]
    const int b   = blockIdx.z;
    const int h   = blockIdx.y;
    const int tid = threadIdx.x;
    const int w    = tid >> 6;              // 4 waves
    const int lane = tid & 63;
    const int q    = lane >> 4;
    const int r    = lane & 15;
    short* Pw = Pbuf + w * (64 * 36);

    // Q fragments: direct 16B vector loads from the fused-emitted frag buffer
    short8 qhi[2][2], qlo[2][2];                 // [row-tile][k-chunk]
    #pragma unroll
    for (int rt = 0; rt < 2; ++rt) {
        const int nt = blockIdx.x * 8 + w * 2 + rt;
        #pragma unroll
        for (int c = 0; c < 2; ++c) {
            size_t off = ((((size_t)(b * 8 + h) * 64 + nt) * 2 + c) * 64 + lane) * 8;
            qhi[rt][c] = *(const short8*)&qhi_g[off];
            qlo[rt][c] = *(const short8*)&qlo_g[off];
        }
    }

    // ones B-frag (bf16 1.0) for the l = P*1 row-sum MFMA
    short8 bones;
    #pragma unroll
    for (int j = 0; j < 8; ++j) bones[j] = (short)0x3F80;

    f32x4 oacc[2][4], lacc[2];
    float m_[2][4];
    #pragma unroll
    for (int rt = 0; rt < 2; ++rt) {
        #pragma unroll
        for (int tt = 0; tt < 4; ++tt) oacc[rt][tt] = (f32x4){0.f, 0.f, 0.f, 0.f};
        lacc[rt] = (f32x4){0.f, 0.f, 0.f, 0.f};
        #pragma unroll
        for (int i = 0; i < 4; ++i) m_[rt][i] = -1e30f;
    }

    for (int t = 0; t < 16; ++t) {
        __syncthreads();
        const size_t kb = ((size_t)(b * 16 + t) * 8) * 512;
        for (int ch = w; ch < 8; ch += 4) {
            dma16(khi_g + kb + ch * 512 + lane * 8, &Khi[ch * 512]);
            dma16(klo_g + kb + ch * 512 + lane * 8, &Klo[ch * 512]);
            dma16(vf_g  + kb + ch * 512 + lane * 8, &Vf [ch * 512]);
        }
        __syncthreads();

        // S (log2-scaled) = Q K^T  (hi*hi + hi*lo + lo*hi); kh/kl shared by 2 rt
        f32x4 s[2][4];
        #pragma unroll
        for (int rt = 0; rt < 2; ++rt)
            #pragma unroll
            for (int tt = 0; tt < 4; ++tt) s[rt][tt] = (f32x4){0.f, 0.f, 0.f, 0.f};
        #pragma unroll
        for (int c = 0; c < 2; ++c) {
            #pragma unroll
            for (int tt = 0; tt < 4; ++tt) {
                short8 kh = *(short8*)&Khi[((tt * 2 + c) * 64 + lane) * 8];
                short8 kl = *(short8*)&Klo[((tt * 2 + c) * 64 + lane) * 8];
                #pragma unroll
                for (int rt = 0; rt < 2; ++rt) {
                    s[rt][tt] = __builtin_amdgcn_mfma_f32_16x16x32_bf16(qhi[rt][c], kh, s[rt][tt], 0, 0, 0);
                    s[rt][tt] = __builtin_amdgcn_mfma_f32_16x16x32_bf16(qhi[rt][c], kl, s[rt][tt], 0, 0, 0);
                    s[rt][tt] = __builtin_amdgcn_mfma_f32_16x16x32_bf16(qlo[rt][c], kh, s[rt][tt], 0, 0, 0);
                }
            }
        }

        // online softmax (log2 space): max shuffles only; sum comes from MFMA
        #pragma unroll
        for (int rt = 0; rt < 2; ++rt) {
            #pragma unroll
            for (int reg = 0; reg < 4; ++reg) {
                float smax = fmaxf(fmaxf(s[rt][0][reg], s[rt][1][reg]),
                                   fmaxf(s[rt][2][reg], s[rt][3][reg]));
                #pragma unroll
                for (int off = 1; off < 16; off <<= 1)
                    smax = fmaxf(smax, __shfl_xor(smax, off, 16));
                float nm    = fmaxf(m_[rt][reg], smax);
                float alpha = exp2f(m_[rt][reg] - nm);
                m_[rt][reg] = nm;
                #pragma unroll
                for (int tt = 0; tt < 4; ++tt)
                    s[rt][tt][reg] = exp2f(s[rt][tt][reg] - nm);
                lacc[rt][reg] *= alpha;
                #pragma unroll
                for (int tt = 0; tt < 4; ++tt) oacc[rt][tt][reg] *= alpha;
            }
        }

        // P -> per-wave LDS (col-major, stride 36): b64 writes, truncation
        #pragma unroll
        for (int rt = 0; rt < 2; ++rt) {
            #pragma unroll
            for (int tt = 0; tt < 4; ++tt) {
                short4v p4;
                #pragma unroll
                for (int reg = 0; reg < 4; ++reg) p4[reg] = bf16tr(s[rt][tt][reg]);
                *(short4v*)&Pw[(r + 16 * tt) * 36 + rt * 16 + q * 4] = p4;
            }
        }

        // O += P V ; l += P 1  (vfr shared by both rt)
        #pragma unroll
        for (int c = 0; c < 2; ++c) {
            short8 pf[2];
            #pragma unroll
            for (int rt = 0; rt < 2; ++rt)
                #pragma unroll
                for (int j = 0; j < 8; ++j)
                    pf[rt][j] = Pw[(c * 32 + q * 8 + j) * 36 + rt * 16 + r];
            #pragma unroll
            for (int rt = 0; rt < 2; ++rt)
                lacc[rt] = __builtin_amdgcn_mfma_f32_16x16x32_bf16(pf[rt], bones, lacc[rt], 0, 0, 0);
            #pragma unroll
            for (int tt = 0; tt < 4; ++tt) {
                short8 vfr = *(short8*)&Vf[((tt * 2 + c) * 64 + lane) * 8];
                #pragma unroll
                for (int rt = 0; rt < 2; ++rt)
                    oacc[rt][tt] = __builtin_amdgcn_mfma_f32_16x16x32_bf16(pf[rt], vfr, oacc[rt][tt], 0, 0, 0);
            }
        }
    }

    // epilogue: normalize, write O as bf16 B-frags (layout verified R4-R8)
    #pragma unroll
    for (int rt = 0; rt < 2; ++rt) {
        const int nt = blockIdx.x * 8 + w * 2 + rt;
        #pragma unroll
        for (int reg = 0; reg < 4; ++reg) {
            float inv = 1.f / lacc[rt][reg];
            #pragma unroll
            for (int tt = 0; tt < 4; ++tt) {
                int ct = h * 2 + (tt >> 1);
                int lanep = ((tt & 1) * 2 + (r >> 3)) * 16 + q * 4 + reg;
                ob[((((size_t)b * 64 + nt) * 16 + ct) * 64 + lanep) * 8 + (r & 7)] =
                    bf16rn(oacc[rt][tt][reg] * inv);
            }
        }
    }
}

// ---------------------------------------------------------------------------
// out_gemm: plain bf16 MFMA, double-buffered staging (kept from R8).
// BM=64(d) BN=64(n) BK=64(c), 4 waves, grid (16,8,8)=1024 blocks; LDS 32 KB.
// ---------------------------------------------------------------------------
__global__ __launch_bounds__(256) void out_gemm(const short* __restrict__ wof,
                                                const short* __restrict__ obf,
                                                float* __restrict__ out) {
    __shared__ short Ah[2][4096];   // [mtl4][kc2][lane][8]
    __shared__ short Bh[2][4096];   // [ntl4][kc2][lane][8]
    const int b = blockIdx.z, bd = blockIdx.y, bn = blockIdx.x;
    const int tid = threadIdx.x, w = tid >> 6, lane = tid & 63;
    const int q = lane >> 4, r = lane & 15;
    f32x4 acc[4];
    #pragma unroll
    for (int j = 0; j < 4; ++j) acc[j] = (f32x4){0.f, 0.f, 0.f, 0.f};

    // prefetch it=0 into buffer 0
    for (int u = w; u < 8; u += 4) {
        size_t ga = ((size_t)((bd * 4 + (u >> 1)) * 16 + (u & 1))) * 512 + lane * 8;
        dma16(wof + ga, &Ah[0][u * 512]);
        size_t gb = ((size_t)((b * 64 + bn * 4 + (u >> 1)) * 16 + (u & 1))) * 512 + lane * 8;
        dma16(obf + gb, &Bh[0][u * 512]);
    }

    for (int it = 0; it < 8; ++it) {
        const int cur = it & 1;
        __syncthreads();
        if (it < 7) {
            for (int u = w; u < 8; u += 4) {
                size_t ga = ((size_t)((bd * 4 + (u >> 1)) * 16 + (it + 1) * 2 + (u & 1))) * 512 + lane * 8;
                dma16(wof + ga, &Ah[cur ^ 1][u * 512]);
                size_t gb = ((size_t)((b * 64 + bn * 4 + (u >> 1)) * 16 + (it + 1) * 2 + (u & 1))) * 512 + lane * 8;
                dma16(obf + gb, &Bh[cur ^ 1][u * 512]);
            }
        }
        #pragma unroll
        for (int kc = 0; kc < 2; ++kc) {
            short8 a = *(short8*)&Ah[cur][(w * 2 + kc) * 512 + lane * 8];
            #pragma unroll
            for (int tt = 0; tt < 4; ++tt) {
                short8 bb = *(short8*)&Bh[cur][(tt * 2 + kc) * 512 + lane * 8];
                acc[tt] = __builtin_amdgcn_mfma_f32_16x16x32_bf16(a, bb, acc[tt], 0, 0, 0);
            }
        }
    }
    const int d_base = bd * 64 + w * 16;
    #pragma unroll
    for (int reg = 0; reg < 4; ++reg)
        #pragma unroll
        for (int tt = 0; tt < 4; ++tt)
            out[((size_t)b * DOUT + d_base + q * 4 + reg) * NTOK
                + bn * 64 + tt * 16 + r] = acc[tt][reg];
}

// ---------------------------------------------------------------------------
extern "C" void kernel_launch(void* const* d_in, const int* in_sizes, int n_in,
                              void* d_out, int out_size, void* d_ws, size_t ws_size,
                              hipStream_t stream) {
    const float* x  = (const float*)d_in[0];
    const float* qp = (const float*)d_in[1];
    const float* kp = (const float*)d_in[2];
    const float* vp = (const float*)d_in[3];
    const float* op = (const float*)d_in[4];
    float* out = (float*)d_out;

    // workspace layout: 19,005,440 shorts = 38.0 MB (< proven 39.06 MB)
    short* Whi = (short*)d_ws;                 // 327,680
    short* Wlo = Whi + 327680;                 // 327,680
    short* Xhi = Wlo + 327680;                 // 4,194,304
    short* Xlo = Xhi + 4194304;                // 4,194,304
    short* Qhi = Xlo + 4194304;                // 4,194,304
    short* Qlo = Qhi + 4194304;                // 4,194,304
    short* Khi = Qlo + 4194304;                // 524,288
    short* Klo = Khi + 524288;                 // 524,288
    short* Vf  = Klo + 524288;                 // 524,288
    // aliases (safe by stream ordering; X dead after qkv_gemm):
    short* Ob  = Xhi;                          // 4,194,304 (attn output)
    short* Wof = Xlo;                          // 262,144

    prepack_w   <<<160,  256, 0, stream>>>(qp, kp, vp, Whi, Wlo);
    prepack_x   <<<2048, 256, 0, stream>>>(x, Xhi, Xlo);
    qkv_gemm    <<<dim3(10, 16, BATCH), 256, 0, stream>>>(Xhi, Xlo, Whi, Wlo,
                                                          Khi, Klo, Vf, Qhi, Qlo);
    prepack_wout<<<128,  256, 0, stream>>>(op, Wof);
    attn_mfma   <<<dim3(8, NH, BATCH), 256, 0, stream>>>(Qhi, Qlo, Khi, Klo, Vf, Ob);
    out_gemm    <<<dim3(16, 8, BATCH), 256, 0, stream>>>(Wof, Ob, out);
}